// Round 10
// baseline (2353.703 us; speedup 1.0000x reference)
//
#include <hip/hip_runtime.h>
#include <math.h>

#define HID 256
#define TWOH 512
#define ROWS 8192   // B*S
#define NLAYER 4
#define TMAX 50
#define DT 0.05f
#define EPSC 1e-3f

typedef float f32x4 __attribute__((ext_vector_type(4)));
typedef unsigned char u8;

// fp8 helpers (OCP e4m3 on gfx950)
__device__ inline u8 f32_to_fp8(float v) {
    return (u8)(__builtin_amdgcn_cvt_pk_fp8_f32(v, v, 0, 0) & 0xff);
}

// ---------------------------------------------------------------------------
// Fragment-major fp8 weight packing (8-wave split, R7 layout).
// Wave wv owns d-range [wv*32, wv*32+32): nt 0,1 -> tau cols (d = wv*32 +
// (nt&1)*16 + l15); nt 2,3 -> forcing cols (same d mapping).
// Fragment (L,wv,ci,nt) is 512 B contiguous at (((L*8+wv)*16+ci)*4+nt)*512:
// lane*8 + j, k = ci*32 + quad*8 + j.
// tau row d: Wt[d][k]; forcing row d: k<256 ? Wi[d][k] : Ws[d][k-256].
// ---------------------------------------------------------------------------
__global__ void pack_w_kernel(const float* __restrict__ Ws,
                              const float* __restrict__ Wi,
                              const float* __restrict__ Wt,
                              u8* __restrict__ Wf) {
    int e = blockIdx.x * 256 + threadIdx.x;     // [0, 2^20)
    int j    = e & 7;
    int lane = (e >> 3) & 63;
    int nt   = (e >> 9) & 3;
    int ci   = (e >> 11) & 15;
    int wv   = (e >> 15) & 7;
    int L    = (e >> 18);
    int l15  = lane & 15;
    int quad = lane >> 4;
    int d = wv * 32 + (nt & 1) * 16 + l15;
    int k = ci * 32 + quad * 8 + j;
    float v;
    if ((nt >> 1) == 0) {
        v = Wt[(size_t)L * HID * TWOH + (size_t)d * TWOH + k];
    } else {
        v = (k < HID) ? Wi[(size_t)L * HID * HID + (size_t)d * HID + k]
                      : Ws[(size_t)L * HID * HID + (size_t)d * HID + (k - HID)];
    }
    Wf[e] = f32_to_fp8(v);
}

__global__ void pack_b_kernel(const float* __restrict__ bs,
                              const float* __restrict__ bi,
                              const float* __restrict__ bt,
                              float* __restrict__ bp) {
    int idx = blockIdx.x * 256 + threadIdx.x;   // [0, 4*512): L*512 + 2d(+1)
    int L = idx / TWOH;
    int n = idx % TWOH;
    int d = n >> 1;
    bp[idx] = ((n & 1) == 0) ? bt[L * HID + d]
                             : (bs[L * HID + d] + bi[L * HID + d]);
}

// ---------------------------------------------------------------------------
// Persistent kernel, 512 threads (8 waves, proven no-spill codegen).
// Block b owns rows [32b, 32b+32). fp32 h state lives in REGISTERS of its
// updater thread (hreg[L][ntp][mt][r], statically indexed via unrolled L).
// LDS holds fp8 copies for the MFMA A-operand only, PING-PONG buffered ->
// ONE barrier per layer-step. Weight fragments stream L2->registers with
// depth-4 modulo prefetch that crosses layer-step boundaries.
// ---------------------------------------------------------------------------
__global__ __launch_bounds__(512, 1) void persistent_kernel(
    const float* __restrict__ x,
    const u8* __restrict__ Wf,
    const float* __restrict__ bp,
    float* __restrict__ deltas,
    float* __restrict__ out)
{
    __shared__ u8 sX[32 * 256];              //  8 KB
    __shared__ u8 sH[2][NLAYER][32 * 256];   // 64 KB (ping-pong fp8 states)
    __shared__ float2 sBias[NLAYER][256];    //  8 KB
    __shared__ float sRed[8];

    const int tid  = threadIdx.x;
    const int lane = tid & 63;
    const int wv   = tid >> 6;               // 0..7
    const int l15  = lane & 15;
    const int quad = lane >> 4;              // 0..3
    const int w32  = wv * 32;                // wave's d-base
    const size_t rowbase = (size_t)blockIdx.x * 32;

    // ---- stage x -> sX (fp8, swizzled); zero both sH buffers; bias table ----
    #pragma unroll
    for (int it = 0; it < 2; ++it) {
        int s = tid + it * 512;              // 32 rows x 32 segs
        int r = s >> 5, seg = s & 31;
        const float* gx = x + (rowbase + r) * HID + seg * 8;
        float4 v0 = *(const float4*)gx;
        float4 v1 = *(const float4*)(gx + 4);
        int lo = __builtin_amdgcn_cvt_pk_fp8_f32(v0.x, v0.y, 0, 0);
        lo     = __builtin_amdgcn_cvt_pk_fp8_f32(v0.z, v0.w, lo, 1);
        int hi = __builtin_amdgcn_cvt_pk_fp8_f32(v1.x, v1.y, 0, 0);
        hi     = __builtin_amdgcn_cvt_pk_fp8_f32(v1.z, v1.w, hi, 1);
        long pk = ((long)(unsigned int)lo) | ((long)hi << 32);
        *(long*)&sX[r * 256 + (seg ^ r) * 8] = pk;
    }
    {
        long* hflat = (long*)&sH[0][0][0];   // 8192 longs total (64 KB)
        #pragma unroll
        for (int it = 0; it < 16; ++it) hflat[tid + it * 512] = 0;
    }
    #pragma unroll
    for (int it = 0; it < 2; ++it) {
        int i = tid + it * 512;              // [0,1024): L = i>>8, d = i&255
        sBias[i >> 8][i & 255] = *(const float2*)(bp + (i >> 8) * TWOH + 2 * (i & 255));
    }
    __syncthreads();

    // ---- fp32 h state in registers (statically indexed; L-loop unrolled) ----
    float hreg[NLAYER][2][2][4];
    #pragma unroll
    for (int L = 0; L < NLAYER; ++L)
        #pragma unroll
        for (int ntp = 0; ntp < 2; ++ntp)
            #pragma unroll
            for (int mt = 0; mt < 2; ++mt)
                #pragma unroll
                for (int r = 0; r < 4; ++r) hreg[L][ntp][mt][r] = 0.0f;

    // ---- preload weight fragment groups 0..3 of (t=0, L=0) ----
    long bb[4][4];
    {
        const u8* wb0 = Wf + (size_t)wv * 32768 + (size_t)lane * 8;
        #pragma unroll
        for (int pi = 0; pi < 4; ++pi)
            #pragma unroll
            for (int nt = 0; nt < 4; ++nt)
                bb[pi][nt] = *(const long*)(wb0 + (size_t)(pi * 4 + nt) * 512);
    }

    for (int t = 0; t < TMAX; ++t) {
        const int pt = t & 1;
        float dmax = 0.0f;
        #pragma unroll
        for (int L = 0; L < NLAYER; ++L) {
            const u8* Alo  = (L == 0) ? sX : sH[pt ^ 1][L - 1]; // cur_in (this t)
            const u8* Ahi  = sH[pt][L];                         // h_prev (last t)
            u8*       Hdst = sH[pt ^ 1][L];                     // h_new fp8 copy
            const u8* wbc = Wf + (size_t)(L * 8 + wv) * 32768 + (size_t)lane * 8;
            const u8* wbn = Wf + (size_t)((((L + 1) & 3) * 8) + wv) * 32768 + (size_t)lane * 8;

            f32x4 acc[2][4];
            #pragma unroll
            for (int mt = 0; mt < 2; ++mt)
                #pragma unroll
                for (int nt = 0; nt < 4; ++nt)
                    acc[mt][nt] = (f32x4){0.f, 0.f, 0.f, 0.f};

            #pragma unroll
            for (int ci = 0; ci < 16; ++ci) {            // k = 32*ci
                const int p = ci & 3;
                const u8* Asrc = (ci < 8) ? Alo : Ahi;   // static under unroll
                const int seg = (ci & 7) * 4 + quad;     // 8-B seg in [0,32)
                long a[2];
                #pragma unroll
                for (int mt = 0; mt < 2; ++mt) {
                    int row = mt * 16 + l15;
                    a[mt] = *(const long*)&Asrc[row * 256 + ((seg ^ row) * 8)];
                }
                #pragma unroll
                for (int mt = 0; mt < 2; ++mt)
                    #pragma unroll
                    for (int nt = 0; nt < 4; ++nt)
                        acc[mt][nt] = __builtin_amdgcn_mfma_f32_16x16x32_fp8_fp8(
                            a[mt], bb[p][nt], acc[mt][nt], 0, 0, 0);
                // modulo prefetch: groups ci+4 of this layer, then the NEXT
                // layer-step's groups 0..3 (in flight across the barrier).
                if (ci < 12) {
                    #pragma unroll
                    for (int nt = 0; nt < 4; ++nt)
                        bb[p][nt] = *(const long*)(wbc + (size_t)((ci + 4) * 4 + nt) * 512);
                } else {
                    #pragma unroll
                    for (int nt = 0; nt < 4; ++nt)
                        bb[p][nt] = *(const long*)(wbn + (size_t)((ci - 12) * 4 + nt) * 512);
                }
            }

            // Epilogue: h from registers (fp32), fp8 copy written to pong
            // buffer. C/D: col = l15 (+16*ntp tile), row = quad*4 + r + 16*mt.
            // tau-pre = acc[mt][ntp], forcing-pre = acc[mt][ntp+2], same lane.
            #pragma unroll
            for (int ntp = 0; ntp < 2; ++ntp) {
                const int d = w32 + ntp * 16 + l15;
                const float2 bb2 = sBias[L][d];
                const int seg = d >> 3, dlow = d & 7;
                #pragma unroll
                for (int mt = 0; mt < 2; ++mt) {
                    #pragma unroll
                    for (int r = 0; r < 4; ++r) {
                        float tpre = acc[mt][ntp][r]     + bb2.x;
                        float fpre = acc[mt][ntp + 2][r] + bb2.y;
                        tpre = fminf(30.f, fmaxf(-30.f, tpre));
                        fpre = fminf(15.f, fmaxf(-15.f, fpre));
                        // h/(sigma(t)+1e-6) == h*(1+u)/(1+eps+eps*u), u=e^-t
                        float u   = __expf(-tpre);
                        float den = 1.0f + 1e-6f + 1e-6f * u;
                        float rcp = __builtin_amdgcn_rcpf(den);
                        float e2  = __expf(2.0f * fpre);
                        float r2  = __builtin_amdgcn_rcpf(e2 + 1.0f);
                        float fo  = (e2 - 1.0f) * r2;
                        float h   = hreg[L][ntp][mt][r];
                        float g   = h * (1.0f + u) * rcp;
                        float nv  = h + DT * (fo - g);
                        nv = fminf(10.0f, fmaxf(-10.0f, nv));
                        hreg[L][ntp][mt][r] = nv;
                        const int row = mt * 16 + quad * 4 + r;
                        Hdst[row * 256 + (seg ^ row) * 8 + dlow] = f32_to_fp8(nv);
                        dmax = fmaxf(dmax, fabsf(nv - h));
                    }
                }
            }
            if (L == NLAYER - 1) {
                #pragma unroll
                for (int off = 32; off > 0; off >>= 1)
                    dmax = fmaxf(dmax, __shfl_xor(dmax, off));
                if (lane == 0) sRed[wv] = dmax;
            }
            __syncthreads();   // ONE barrier per layer-step: h_new visible
        } // L

        if (tid == 0) {
            float m = sRed[0];
            #pragma unroll
            for (int w = 1; w < 8; ++w) m = fmaxf(m, sRed[w]);
            atomicMax((unsigned int*)(deltas + t), __float_as_uint(m));
        }
    } // t

    // ---- final output: layer-3 fp32 states straight from registers ----
    #pragma unroll
    for (int ntp = 0; ntp < 2; ++ntp) {
        const int d = w32 + ntp * 16 + l15;
        #pragma unroll
        for (int mt = 0; mt < 2; ++mt)
            #pragma unroll
            for (int r = 0; r < 4; ++r) {
                const int row = mt * 16 + quad * 4 + r;
                out[(rowbase + row) * HID + d] = hreg[NLAYER - 1][ntp][mt][r];
            }
    }
}

__global__ void result_kernel(const float* __restrict__ deltas,
                              float* __restrict__ out) {
    if (threadIdx.x == 0) {
        int res = TMAX;
        for (int t = 0; t < TMAX; ++t) {
            if (deltas[t] < EPSC) { res = t; break; }
        }
        out[(size_t)ROWS * HID] = (float)res;
    }
}

// ---------------------------------------------------------------------------
extern "C" void kernel_launch(void* const* d_in, const int* in_sizes, int n_in,
                              void* d_out, int out_size, void* d_ws, size_t ws_size,
                              hipStream_t stream) {
    const float* x  = (const float*)d_in[0];
    const float* Ws = (const float*)d_in[1];
    const float* bs = (const float*)d_in[2];
    const float* Wi = (const float*)d_in[3];
    const float* bi = (const float*)d_in[4];
    const float* Wt = (const float*)d_in[5];
    const float* bt = (const float*)d_in[6];
    float* out = (float*)d_out;

    char* p = (char*)d_ws;
    u8*    Wf     = (u8*)p;    p += (size_t)NLAYER * TWOH * TWOH;            // 1 MB
    float* bp     = (float*)p; p += (size_t)NLAYER * TWOH * sizeof(float);   // 8 KB
    float* deltas = (float*)p; p += 64 * sizeof(float);

    hipMemsetAsync(deltas, 0, 64 * sizeof(float), stream);
    pack_w_kernel<<<(NLAYER * TWOH * TWOH) / 256, 256, 0, stream>>>(Ws, Wi, Wt, Wf);
    pack_b_kernel<<<(NLAYER * TWOH) / 256, 256, 0, stream>>>(bs, bi, bt, bp);

    persistent_kernel<<<256, 512, 0, stream>>>(x, Wf, bp, deltas, out);
    result_kernel<<<1, 64, 0, stream>>>(deltas, out);
}